// Round 2
// baseline (5211.619 us; speedup 1.0000x reference)
//
#include <hip/hip_runtime.h>
#include <math.h>

#define N 1024
#define NN (1024*1024)
#define BATCH 8

static constexpr float MU1 = 1e-6f, MU2 = 1e-5f, MU3 = 1e-5f;

__device__ __forceinline__ float2 cmulf(float2 a, float2 b){
  return make_float2(a.x*b.x - a.y*b.y, a.x*b.y + a.y*b.x);
}
__device__ __forceinline__ float softf(float v, float T){
  float a = fmaxf(fabsf(v) - T, 0.f);
  return copysignf(a, v);
}

// ---------------- 1024-pt Stockham radix-2 FFT in LDS ----------------
// Caller fills bufA then __syncthreads(). Result lands back in bufA.
// DIR=-1 forward (e^{-i·}), DIR=+1 inverse (e^{+i·}, unnormalized).
template<int DIR>
__device__ __forceinline__ void fft1024(float2* bufA, float2* bufB,
                                        const float2* Ws, int tid){
  float2* cur = bufA; float2* oth = bufB;
  int s = 1;
  for (int st = 0; st < 10; ++st){
    int m = 512 >> st;
    #pragma unroll
    for (int bb = 0; bb < 2; ++bb){
      int b = tid + bb*256;
      int p = b >> st;
      int q = b & (s-1);
      float2 a = cur[b];            // q + s*p == b
      float2 c = cur[b + 512];      // q + s*(p+m)
      float2 w = Ws[b & ~(s-1)];    // = W^(p*s)
      if (DIR > 0) w.y = -w.y;
      float2 d = make_float2(a.x - c.x, a.y - c.y);
      oth[q + s*(2*p)]   = make_float2(a.x + c.x, a.y + c.y);
      oth[q + s*(2*p+1)] = cmulf(d, w);
    }
    __syncthreads();
    float2* t = cur; cur = oth; oth = t;
    s <<= 1;
  }
  // 10 swaps -> result in bufA
}

// ---------------- precompute ----------------
__global__ void k_twiddle(float2* W){
  int j = blockIdx.x*blockDim.x + threadIdx.x;
  if (j < 512){
    double a = -2.0 * M_PI * (double)j / 1024.0;
    W[j] = make_float2((float)cos(a), (float)sin(a));
  }
}

__global__ void k_build_h(const float* __restrict__ h, float2* __restrict__ Z){
  int idx = blockIdx.x*256 + threadIdx.x; // NN
  int i = idx >> 10, j = idx & 1023;
  float v = 0.f;
  if (i >= 256 && i < 768 && j >= 256 && j < 768)
    v = h[(i-256)*512 + (j-256)];
  Z[idx] = make_float2(v, 0.f);
}

// Zt[k1][k0] = fft2(pad h); HfT = (-1)^(k0+k1)*Zt; RdivT folds 1/N^2 ifft scale
__global__ void k_filters(const float2* __restrict__ Zt, float2* __restrict__ HfT,
                          float* __restrict__ RdivT){
  int idx = blockIdx.x*256 + threadIdx.x;
  int k1 = idx >> 10, k0 = idx & 1023;
  float2 v = Zt[idx];
  float sgn = ((k0 + k1) & 1) ? -1.f : 1.f;
  HfT[idx] = make_float2(sgn*v.x, sgn*v.y);
  double mag2 = (double)v.x*(double)v.x + (double)v.y*(double)v.y;
  double ltl = 4.0 - 2.0*cos(2.0*M_PI*(double)k0/1024.0)
                   - 2.0*cos(2.0*M_PI*(double)k1/1024.0);
  double rd = 1.0 / ((double)MU1*mag2 + (double)MU2*ltl + (double)MU3);
  RdivT[idx] = (float)(rd / ((double)N * (double)N));
}

// X=G0=G1=K=0 ; M0 = MU1 * Vdiv * CTy
__global__ void k_init(float* __restrict__ X, float* __restrict__ G0,
                       float* __restrict__ G1, float* __restrict__ K,
                       float* __restrict__ M, const float* __restrict__ y){
  int idx = blockIdx.x*256 + threadIdx.x; // BATCH*NN
  int e = idx >> 20, r = (idx >> 10) & 1023, c = idx & 1023;
  X[idx] = 0.f; G0[idx] = 0.f; G1[idx] = 0.f; K[idx] = 0.f;
  float m = 0.f;
  if (r >= 256 && r < 768 && c >= 256 && c < 768)
    m = y[(size_t)e*262144 + (size_t)(r-256)*512 + (c-256)] * (MU1/(1.f + MU1));
  M[idx] = m;
}

// ---------------- G (U-dual) update: needs psi(X) ----------------
__global__ void k_ka(const float* __restrict__ X, float* __restrict__ G0,
                     float* __restrict__ G1){
  int idx = blockIdx.x*256 + threadIdx.x; // BATCH*NN
  int e = idx >> 20, r = (idx >> 10) & 1023, c = idx & 1023;
  size_t eb = (size_t)e * NN;
  float x   = X[idx];
  float xmr = X[eb + (size_t)((r-1)&1023)*N + c];
  float xmc = X[eb + (size_t)r*N + ((c-1)&1023)];
  float psi0 = xmr - x, psi1 = xmc - x;
  float g0 = G0[idx], g1 = G1[idx];
  const float T = 1e4f;              // TAU/MU2
  float u0 = softf(2.f*psi0 - g0*(1.f/MU2), T);
  float u1 = softf(2.f*psi1 - g1*(1.f/MU2), T);
  G0[idx] = MU2*(u0 - psi0) + g0;
  G1[idx] = MU2*(u1 - psi1) + g1;
}

// ---------------- p1: z = s + i*M per row, forward row FFT ----------------
// s = K + psit(G) = K + (G0[i+1,j]-G0[i,j]) + (G1[i,j+1]-G1[i,j])
__global__ __launch_bounds__(256) void k_p1(const float* __restrict__ G0,
                                            const float* __restrict__ G1,
                                            const float* __restrict__ K,
                                            const float* __restrict__ M,
                                            float2* __restrict__ Z,
                                            const float2* __restrict__ Wg, int e0){
  __shared__ float2 bufA[N], bufB[N], Ws[512];
  int tid = threadIdx.x;
  int i = blockIdx.x, c = blockIdx.y, e = e0 + c;
  size_t rb  = (size_t)e*NN + (size_t)i*N;
  size_t rb1 = (size_t)e*NN + (size_t)((i+1)&1023)*N;
  size_t zb  = (size_t)c*NN + (size_t)i*N;
  for (int k = tid; k < 512; k += 256) Ws[k] = Wg[k];
  for (int j = tid; j < N; j += 256){
    int jp = (j+1) & 1023;
    float s = K[rb+j] + (G0[rb1+j] - G0[rb+j]) + (G1[rb+jp] - G1[rb+j]);
    bufA[j] = make_float2(s, M[rb+j]);
  }
  __syncthreads();
  fft1024<-1>(bufA, bufB, Ws, tid);
  for (int j = tid; j < N; j += 256) Z[zb+j] = bufA[j];
}

// ---------------- generic in-place row FFT pass ----------------
template<int DIR>
__global__ __launch_bounds__(256) void k_fft_row(float2* Z, const float2* __restrict__ Wg){
  __shared__ float2 bufA[N], bufB[N], Ws[512];
  int tid = threadIdx.x;
  size_t base = ((size_t)blockIdx.y * N + blockIdx.x) * N;
  for (int k = tid; k < 512; k += 256) Ws[k] = Wg[k];
  for (int k = tid; k < N; k += 256) bufA[k] = Z[base + k];
  __syncthreads();
  fft1024<DIR>(bufA, bufB, Ws, tid);
  for (int k = tid; k < N; k += 256) Z[base + k] = bufA[k];
}

// ---------------- in-place square transpose (tile-pair swap) ----------------
__global__ void k_transpose_ip(float2* Z){
  __shared__ float2 ta[32][33], tb[32][33];
  int t = blockIdx.x, ti = 0;
  while (t >= 32 - ti){ t -= 32 - ti; ti++; }
  int tj = ti + t;
  size_t base = (size_t)blockIdx.y * NN;
  int ra = ti*32, ca = tj*32;     // tile A origin; tile B origin = (ca, ra)
  for (int k = threadIdx.y; k < 32; k += 8){
    ta[k][threadIdx.x] = Z[base + (size_t)(ra+k)*N + ca + threadIdx.x];
    if (ti != tj)
      tb[k][threadIdx.x] = Z[base + (size_t)(ca+k)*N + ra + threadIdx.x];
  }
  __syncthreads();
  for (int k = threadIdx.y; k < 32; k += 8){
    Z[base + (size_t)(ra+k)*N + ca + threadIdx.x] = (ti!=tj) ? tb[threadIdx.x][k]
                                                             : ta[threadIdx.x][k];
    if (ti != tj)
      Z[base + (size_t)(ca+k)*N + ra + threadIdx.x] = ta[threadIdx.x][k];
  }
}

// ---------------- p3: in-place spectral combine on (k,-k) pairs ----------------
// Z holds fft2(s+iM) transposed [k1][k0]. Unpack S,Mf; Fx=Rdiv*(S+conj(Hf)Mf);
// Y[k]=Fx*(1+iHf) -> ifft gives X + i*Hx.  Y[-k]=conj(Fx*(1-iHf)).
__global__ void k_p3(float2* __restrict__ Z, const float2* __restrict__ HfT,
                     const float* __restrict__ RdivT){
  int t = blockIdx.x*256 + threadIdx.x; // CH*NN
  int c = t >> 20;
  int idx = t & (NN-1);
  int k1 = idx >> 10, k0 = idx & 1023;
  int ridx = (((N-k1)&1023) << 10) | ((N-k0)&1023);
  if (idx > ridx) return;
  size_t base = (size_t)c * NN;
  float2 Zk = Z[base+idx], Zr = Z[base+ridx];
  float Sre = 0.5f*(Zk.x + Zr.x);
  float Sim = 0.5f*(Zk.y - Zr.y);
  float Mre = 0.5f*(Zk.y + Zr.y);
  float Mim = 0.5f*(Zr.x - Zk.x);
  float2 hf = HfT[idx];
  float rd = RdivT[idx];
  float fr = rd*(Sre + hf.x*Mre + hf.y*Mim);
  float fi = rd*(Sim + hf.x*Mim - hf.y*Mre);
  float hr = hf.x*fr - hf.y*fi;
  float hi = hf.x*fi + hf.y*fr;
  Z[base+idx]  = make_float2(fr - hi, fi + hr);
  Z[base+ridx] = make_float2(fr + hi, hr - fi);
}

// ---------------- p5: 2nd inverse row FFT; write X; fused K,M updates ----------------
__global__ __launch_bounds__(256) void k_p5(const float2* __restrict__ Z,
                                            float* __restrict__ X, float* __restrict__ K,
                                            float* __restrict__ M, const float* __restrict__ y,
                                            const float2* __restrict__ Wg, int e0){
  __shared__ float2 bufA[N], bufB[N], Ws[512];
  int tid = threadIdx.x;
  int i = blockIdx.x, c = blockIdx.y, e = e0 + c;
  size_t zb = (size_t)c*NN + (size_t)i*N;
  size_t sb = (size_t)e*NN + (size_t)i*N;
  for (int k = tid; k < 512; k += 256) Ws[k] = Wg[k];
  for (int k = tid; k < N; k += 256) bufA[k] = Z[zb + k];
  __syncthreads();
  fft1024<1>(bufA, bufB, Ws, tid);
  bool rcent = (i >= 256 && i < 768);
  for (int j = tid; j < N; j += 256){
    float x = bufA[j].x, hx = bufA[j].y;
    X[sb+j] = x;
    float kk = K[sb+j];
    float w = fmaxf(2.f*x - kk*(1.f/MU3), 0.f);
    K[sb+j] = MU3*(w - x) + kk;
    float m = M[sb+j];
    bool cent = rcent && (j >= 256 && j < 768);
    float cty  = cent ? y[(size_t)e*262144 + (size_t)(i-256)*512 + (j-256)] : 0.f;
    float vdiv = cent ? (1.f/(1.f + MU1)) : (1.f/MU1);
    float v = vdiv*(2.f*MU1*hx - m + cty);
    M[sb+j] = MU1*(v - hx) + m;
  }
}

__global__ void k_crop(const float* __restrict__ X, float* __restrict__ out){
  int t = blockIdx.x*256 + threadIdx.x; // 8*512*512
  int e = t >> 18;
  int r = (t >> 9) & 511;
  int c = t & 511;
  out[t] = X[(size_t)e*NN + (size_t)(r+256)*N + (c+256)];
}

extern "C" void kernel_launch(void* const* d_in, const int* in_sizes, int n_in,
                              void* d_out, int out_size, void* d_ws, size_t ws_size,
                              hipStream_t stream){
  const float* y = (const float*)d_in[0];   // (8,1,512,512)
  const float* h = (const float*)d_in[1];   // (512,512)
  float* out = (float*)d_out;

  size_t fplane = (size_t)BATCH * NN;
  float* X  = (float*)d_ws;
  float* G0 = X  + fplane;
  float* G1 = G0 + fplane;
  float* K  = G1 + fplane;
  float* M  = K  + fplane;
  float2* HfT   = (float2*)(M + fplane);
  float*  RdivT = (float*)(HfT + NN);
  float2* Wtab  = (float2*)(RdivT + NN);
  float2* Zws   = Wtab + 512;
  size_t used = (size_t)((char*)Zws - (char*)d_ws);

  int CH = 0;
  for (int c = BATCH; c >= 1; c >>= 1)
    if (used + (size_t)c * NN * sizeof(float2) <= ws_size){ CH = c; break; }
  float2* Z = (CH > 0) ? Zws : (float2*)d_out;  // d_out is exactly NN float2
  if (CH == 0) CH = 1;

  // precompute: twiddles, Hf, Rdiv (one 2D FFT of padded h, in Z plane 0)
  k_twiddle<<<2, 256, 0, stream>>>(Wtab);
  k_build_h<<<NN/256, 256, 0, stream>>>(h, Z);
  k_fft_row<-1><<<dim3(N,1), 256, 0, stream>>>(Z, Wtab);
  k_transpose_ip<<<dim3(528,1), dim3(32,8), 0, stream>>>(Z);
  k_fft_row<-1><<<dim3(N,1), 256, 0, stream>>>(Z, Wtab);
  k_filters<<<NN/256, 256, 0, stream>>>(Z, HfT, RdivT);
  k_init<<<BATCH*NN/256, 256, 0, stream>>>(X, G0, G1, K, M, y);

  for (int t = 0; t < 20; ++t){
    k_ka<<<BATCH*NN/256, 256, 0, stream>>>(X, G0, G1);
    for (int e0 = 0; e0 < BATCH; e0 += CH){
      k_p1<<<dim3(N,CH), 256, 0, stream>>>(G0, G1, K, M, Z, Wtab, e0);
      k_transpose_ip<<<dim3(528,CH), dim3(32,8), 0, stream>>>(Z);
      k_fft_row<-1><<<dim3(N,CH), 256, 0, stream>>>(Z, Wtab);
      k_p3<<<CH*NN/256, 256, 0, stream>>>(Z, HfT, RdivT);
      k_fft_row<1><<<dim3(N,CH), 256, 0, stream>>>(Z, Wtab);
      k_transpose_ip<<<dim3(528,CH), dim3(32,8), 0, stream>>>(Z);
      k_p5<<<dim3(N,CH), 256, 0, stream>>>(Z, X, K, M, y, Wtab, e0);
    }
  }
  k_crop<<<(BATCH*512*512)/256, 256, 0, stream>>>(X, out);
}

// Round 3
// 4560.114 us; speedup vs baseline: 1.1429x; 1.1429x over previous
//
#include <hip/hip_runtime.h>
#include <math.h>

#define N 1024
#define NN (1024*1024)
#define BATCH 8

static constexpr float MU1 = 1e-6f, MU2 = 1e-5f, MU3 = 1e-5f;

__device__ __forceinline__ float2 cmulf(float2 a, float2 b){
  return make_float2(a.x*b.x - a.y*b.y, a.x*b.y + a.y*b.x);
}
__device__ __forceinline__ float softf(float v, float T){
  float a = fmaxf(fabsf(v) - T, 0.f);
  return copysignf(a, v);
}
__device__ __forceinline__ int bitrev10(int p){ return (int)(__brev((unsigned)p) >> 22); }
// folded column order: pairs (k0, N-k0) adjacent, and any 16-aligned group
// holds complete pairs. fold: 0->0, 512->1, t->2t, 1024-t->2t+1 (t in [1,511])
__device__ __forceinline__ int foldc(int k){
  if (k == 0) return 0;
  if (k == 512) return 1;
  return (k < 512) ? 2*k : 2*(1024-k)+1;
}
__device__ __forceinline__ int unfoldc(int c){
  if (c < 2) return c ? 512 : 0;
  return (c & 1) ? 1024 - ((c-1)>>1) : (c>>1);
}

// ---------------- 1024-pt Stockham radix-2 FFT in LDS ----------------
// Caller fills bufA then __syncthreads(). Result lands back in bufA.
// DIR=-1 forward (e^{-i}), DIR=+1 inverse (e^{+i}, unnormalized).
template<int DIR>
__device__ __forceinline__ void fft1024(float2* bufA, float2* bufB,
                                        const float2* Ws, int tid){
  float2* cur = bufA; float2* oth = bufB;
  int s = 1;
  for (int st = 0; st < 10; ++st){
    int m = 512 >> st;
    #pragma unroll
    for (int bb = 0; bb < 2; ++bb){
      int b = tid + bb*256;
      int p = b >> st;
      int q = b & (s-1);
      float2 a = cur[b];
      float2 c = cur[b + 512];
      float2 w = Ws[b & ~(s-1)];
      if (DIR > 0) w.y = -w.y;
      float2 d = make_float2(a.x - c.x, a.y - c.y);
      oth[q + s*(2*p)]   = make_float2(a.x + c.x, a.y + c.y);
      oth[q + s*(2*p+1)] = cmulf(d, w);
    }
    __syncthreads();
    float2* t = cur; cur = oth; oth = t;
    s <<= 1;
  }
}

// ---------------- precompute ----------------
__global__ void k_twiddle(float2* W){
  int j = blockIdx.x*blockDim.x + threadIdx.x;
  if (j < 512){
    double a = -2.0 * M_PI * (double)j / 1024.0;
    W[j] = make_float2((float)cos(a), (float)sin(a));
  }
}

__global__ void k_build_h(const float* __restrict__ h, float2* __restrict__ Z){
  int idx = blockIdx.x*256 + threadIdx.x; // NN
  int i = idx >> 10, j = idx & 1023;
  float v = 0.f;
  if (i >= 256 && i < 768 && j >= 256 && j < 768)
    v = h[(i-256)*512 + (j-256)];
  Z[idx] = make_float2(v, 0.f);
}

// ZT[idx] = fft2(pad h) at (k_j = idx>>10, k_i = idx&1023).
// Emit HfC/RdC in colpass layout: [p][colp] with k_i=bitrev(p), k_j=unfold(colp).
__global__ void k_filters2(const float2* __restrict__ ZT, float2* __restrict__ HfC,
                           float* __restrict__ RdC){
  int id = blockIdx.x*256 + threadIdx.x; // NN
  int p = id >> 10, cp = id & 1023;
  int ki = bitrev10(p);
  int kj = unfoldc(cp);
  float2 v = ZT[((size_t)kj << 10) | (size_t)ki];
  float sgn = ((ki + kj) & 1) ? -1.f : 1.f;
  HfC[id] = make_float2(sgn*v.x, sgn*v.y);
  double mag2 = (double)v.x*(double)v.x + (double)v.y*(double)v.y;
  double ltl = 4.0 - 2.0*cos(2.0*M_PI*(double)ki/1024.0)
                   - 2.0*cos(2.0*M_PI*(double)kj/1024.0);
  double rd = 1.0 / ((double)MU1*mag2 + (double)MU2*ltl + (double)MU3);
  RdC[id] = (float)(rd / ((double)N * (double)N));
}

// X=G0=G1=K=0 ; M0 = MU1 * Vdiv * CTy
__global__ void k_init(float* __restrict__ X, float* __restrict__ G0,
                       float* __restrict__ G1, float* __restrict__ K,
                       float* __restrict__ M, const float* __restrict__ y){
  int idx = blockIdx.x*256 + threadIdx.x; // BATCH*NN
  int e = idx >> 20, r = (idx >> 10) & 1023, c = idx & 1023;
  X[idx] = 0.f; G0[idx] = 0.f; G1[idx] = 0.f; K[idx] = 0.f;
  float m = 0.f;
  if (r >= 256 && r < 768 && c >= 256 && c < 768)
    m = y[(size_t)e*262144 + (size_t)(r-256)*512 + (c-256)] * (MU1/(1.f + MU1));
  M[idx] = m;
}

// ---------------- G (U-dual) update ----------------
__global__ void k_ka(const float* __restrict__ X, float* __restrict__ G0,
                     float* __restrict__ G1){
  int idx = blockIdx.x*256 + threadIdx.x; // BATCH*NN
  int e = idx >> 20, r = (idx >> 10) & 1023, c = idx & 1023;
  size_t eb = (size_t)e * NN;
  float x   = X[idx];
  float xmr = X[eb + (size_t)((r-1)&1023)*N + c];
  float xmc = X[eb + (size_t)r*N + ((c-1)&1023)];
  float psi0 = xmr - x, psi1 = xmc - x;
  float g0 = G0[idx], g1 = G1[idx];
  const float T = 1e4f;              // TAU/MU2
  float u0 = softf(2.f*psi0 - g0*(1.f/MU2), T);
  float u1 = softf(2.f*psi1 - g1*(1.f/MU2), T);
  G0[idx] = MU2*(u0 - psi0) + g0;
  G1[idx] = MU2*(u1 - psi1) + g1;
}

// ---------------- p1: z = s + i*M per row, row FFT, folded-col write ----------
__global__ __launch_bounds__(256) void k_p1(const float* __restrict__ G0,
                                            const float* __restrict__ G1,
                                            const float* __restrict__ K,
                                            const float* __restrict__ M,
                                            float2* __restrict__ Z,
                                            const float2* __restrict__ Wg, int e0){
  __shared__ float2 bufA[N], bufB[N], Ws[512];
  int tid = threadIdx.x;
  int i = blockIdx.x, c = blockIdx.y, e = e0 + c;
  size_t rb  = (size_t)e*NN + (size_t)i*N;
  size_t rb1 = (size_t)e*NN + (size_t)((i+1)&1023)*N;
  size_t zb  = (size_t)c*NN + (size_t)i*N;
  for (int k = tid; k < 512; k += 256) Ws[k] = Wg[k];
  for (int j = tid; j < N; j += 256){
    int jp = (j+1) & 1023;
    float s = K[rb+j] + (G0[rb1+j] - G0[rb+j]) + (G1[rb+jp] - G1[rb+j]);
    bufA[j] = make_float2(s, M[rb+j]);
  }
  __syncthreads();
  fft1024<-1>(bufA, bufB, Ws, tid);
  // permute into folded column order (bufB free after fft), coalesced write
  for (int j = tid; j < N; j += 256) bufB[foldc(j)] = bufA[j];
  __syncthreads();
  for (int j = tid; j < N; j += 256) Z[zb+j] = bufB[j];
}

// ---------------- generic in-place row FFT (precompute only) ----------------
template<int DIR>
__global__ __launch_bounds__(256) void k_fft_row(float2* Z, const float2* __restrict__ Wg){
  __shared__ float2 bufA[N], bufB[N], Ws[512];
  int tid = threadIdx.x;
  size_t base = ((size_t)blockIdx.y * N + blockIdx.x) * N;
  for (int k = tid; k < 512; k += 256) Ws[k] = Wg[k];
  for (int k = tid; k < N; k += 256) bufA[k] = Z[base + k];
  __syncthreads();
  fft1024<DIR>(bufA, bufB, Ws, tid);
  for (int k = tid; k < N; k += 256) Z[base + k] = bufA[k];
}

// ---------------- in-place square transpose (precompute only) ----------------
__global__ void k_transpose_ip(float2* Z){
  __shared__ float2 ta[32][33], tb[32][33];
  int t = blockIdx.x, ti = 0;
  while (t >= 32 - ti){ t -= 32 - ti; ti++; }
  int tj = ti + t;
  size_t base = (size_t)blockIdx.y * NN;
  int ra = ti*32, ca = tj*32;
  for (int k = threadIdx.y; k < 32; k += 8){
    ta[k][threadIdx.x] = Z[base + (size_t)(ra+k)*N + ca + threadIdx.x];
    if (ti != tj)
      tb[k][threadIdx.x] = Z[base + (size_t)(ca+k)*N + ra + threadIdx.x];
  }
  __syncthreads();
  for (int k = threadIdx.y; k < 32; k += 8){
    Z[base + (size_t)(ra+k)*N + ca + threadIdx.x] = (ti!=tj) ? tb[threadIdx.x][k]
                                                             : ta[threadIdx.x][k];
    if (ti != tj)
      Z[base + (size_t)(ca+k)*N + ra + threadIdx.x] = ta[threadIdx.x][k];
  }
}

// ---------------- fused column pass: DIF fwd cols + spectral combine + DIT inv ----
// Block handles 16 folded columns x 1024 rows (139KB LDS tile, +17 pad: 2-way free).
// Forward DIF leaves bit-reversed row order; p3 done in bitrev position space
// (LDS-local perfect matching); inverse DIT consumes bitrev order -> natural.
#define CPT 512
__global__ __launch_bounds__(CPT) void k_colpass(float2* __restrict__ Z,
    const float2* __restrict__ HfC, const float* __restrict__ RdC,
    const float2* __restrict__ Wg){
  __shared__ float2 tile[1024][17];
  __shared__ float2 Ws[512];
  int tid = threadIdx.x;
  int blk = blockIdx.x;            // 64 column-groups
  size_t zbase = (size_t)blockIdx.y*NN + (size_t)(blk<<4);
  for (int k = tid; k < 512; k += CPT) Ws[k] = Wg[k];
  for (int k = tid; k < 16384; k += CPT){
    int r = k >> 4, c = k & 15;
    tile[r][c] = Z[zbase + (size_t)r*N + c];
  }
  __syncthreads();
  // forward DIF along columns
  for (int s = 0; s <= 9; ++s){
    int half = 512 >> s;
    for (int k = tid; k < 8192; k += CPT){
      int c = k & 15, t = k >> 4;
      int j = t & (half-1);
      int pos = ((t >> (9 - s)) << (10 - s)) + j;
      float2 u = tile[pos][c], v = tile[pos+half][c];
      float2 w = Ws[j << s];
      float2 d = make_float2(u.x - v.x, u.y - v.y);
      tile[pos][c]      = make_float2(u.x + v.x, u.y + v.y);
      tile[pos+half][c] = cmulf(d, w);
    }
    __syncthreads();
  }
  // spectral combine on Hermitian pairs (bitrev position space)
  int colbase = blk << 4;
  for (int k = tid; k < 16384; k += CPT){
    int p = k >> 4, c = k & 15;
    int k1 = bitrev10(p);
    int q = bitrev10((1024 - k1) & 1023);
    int colp = colbase + c;
    int cm = (colp < 2) ? c : (c ^ 1);
    int pid = (q << 4) | cm;
    if (pid < k) continue;
    float2 Zk = tile[p][c];
    float2 Zr = tile[q][cm];
    float Sre = 0.5f*(Zk.x + Zr.x);
    float Sim = 0.5f*(Zk.y - Zr.y);
    float Mre = 0.5f*(Zk.y + Zr.y);
    float Mim = 0.5f*(Zr.x - Zk.x);
    size_t fidx = ((size_t)p << 10) | (size_t)colp;
    float2 hf = HfC[fidx];
    float rd  = RdC[fidx];
    float fr = rd*(Sre + hf.x*Mre + hf.y*Mim);
    float fi = rd*(Sim + hf.x*Mim - hf.y*Mre);
    float hr = hf.x*fr - hf.y*fi;
    float hi = hf.x*fi + hf.y*fr;
    tile[p][c] = make_float2(fr - hi, fi + hr);
    if (pid != k) tile[q][cm] = make_float2(fr + hi, hr - fi);
  }
  __syncthreads();
  // inverse DIT along columns (bitrev in -> natural out, unnormalized)
  for (int s = 0; s <= 9; ++s){
    int half = 1 << s;
    for (int k = tid; k < 8192; k += CPT){
      int c = k & 15, t = k >> 4;
      int j = t & (half-1);
      int pos = ((t >> s) << (s+1)) + j;
      float2 u = tile[pos][c], v = tile[pos+half][c];
      float2 w = Ws[j << (9 - s)]; w.y = -w.y;
      float2 x = cmulf(v, w);
      tile[pos][c]      = make_float2(u.x + x.x, u.y + x.y);
      tile[pos+half][c] = make_float2(u.x - x.x, u.y - x.y);
    }
    __syncthreads();
  }
  for (int k = tid; k < 16384; k += CPT){
    int r = k >> 4, c = k & 15;
    Z[zbase + (size_t)r*N + c] = tile[r][c];
  }
}

// ---------------- p5: unfold + inverse row FFT; write X; fused K,M updates ----
__global__ __launch_bounds__(256) void k_p5(const float2* __restrict__ Z,
                                            float* __restrict__ X, float* __restrict__ K,
                                            float* __restrict__ M, const float* __restrict__ y,
                                            const float2* __restrict__ Wg, int e0){
  __shared__ float2 bufA[N], bufB[N], Ws[512];
  int tid = threadIdx.x;
  int i = blockIdx.x, c = blockIdx.y, e = e0 + c;
  size_t zb = (size_t)c*NN + (size_t)i*N;
  size_t sb = (size_t)e*NN + (size_t)i*N;
  for (int k = tid; k < 512; k += 256) Ws[k] = Wg[k];
  for (int k = tid; k < N; k += 256) bufB[k] = Z[zb + k];   // folded row, contiguous
  __syncthreads();
  for (int k = tid; k < N; k += 256) bufA[k] = bufB[foldc(k)];
  __syncthreads();
  fft1024<1>(bufA, bufB, Ws, tid);
  bool rcent = (i >= 256 && i < 768);
  for (int j = tid; j < N; j += 256){
    float x = bufA[j].x, hx = bufA[j].y;
    X[sb+j] = x;
    float kk = K[sb+j];
    float w = fmaxf(2.f*x - kk*(1.f/MU3), 0.f);
    K[sb+j] = MU3*(w - x) + kk;
    float m = M[sb+j];
    bool cent = rcent && (j >= 256 && j < 768);
    float cty  = cent ? y[(size_t)e*262144 + (size_t)(i-256)*512 + (j-256)] : 0.f;
    float vdiv = cent ? (1.f/(1.f + MU1)) : (1.f/MU1);
    float v = vdiv*(2.f*MU1*hx - m + cty);
    M[sb+j] = MU1*(v - hx) + m;
  }
}

__global__ void k_crop(const float* __restrict__ X, float* __restrict__ out){
  int t = blockIdx.x*256 + threadIdx.x; // 8*512*512
  int e = t >> 18;
  int r = (t >> 9) & 511;
  int c = t & 511;
  out[t] = X[(size_t)e*NN + (size_t)(r+256)*N + (c+256)];
}

extern "C" void kernel_launch(void* const* d_in, const int* in_sizes, int n_in,
                              void* d_out, int out_size, void* d_ws, size_t ws_size,
                              hipStream_t stream){
  const float* y = (const float*)d_in[0];   // (8,1,512,512)
  const float* h = (const float*)d_in[1];   // (512,512)
  float* out = (float*)d_out;

  size_t fplane = (size_t)BATCH * NN;
  float* X  = (float*)d_ws;
  float* G0 = X  + fplane;
  float* G1 = G0 + fplane;
  float* K  = G1 + fplane;
  float* M  = K  + fplane;
  float2* HfC  = (float2*)(M + fplane);
  float*  RdC  = (float*)(HfC + NN);
  float2* Wtab = (float2*)(RdC + NN);
  float2* Zws  = Wtab + 512;
  size_t used = (size_t)((char*)Zws - (char*)d_ws);

  int CH = 0;
  for (int c = BATCH; c >= 1; c >>= 1)
    if (used + (size_t)c * NN * sizeof(float2) <= ws_size){ CH = c; break; }
  float2* Z = (CH > 0) ? Zws : (float2*)d_out;  // d_out is exactly NN float2
  if (CH == 0) CH = 1;

  // precompute: twiddles, fft2(pad h) in Z plane 0, filters in colpass layout
  k_twiddle<<<2, 256, 0, stream>>>(Wtab);
  k_build_h<<<NN/256, 256, 0, stream>>>(h, Z);
  k_fft_row<-1><<<dim3(N,1), 256, 0, stream>>>(Z, Wtab);
  k_transpose_ip<<<dim3(528,1), dim3(32,8), 0, stream>>>(Z);
  k_fft_row<-1><<<dim3(N,1), 256, 0, stream>>>(Z, Wtab);
  k_filters2<<<NN/256, 256, 0, stream>>>(Z, HfC, RdC);
  k_init<<<BATCH*NN/256, 256, 0, stream>>>(X, G0, G1, K, M, y);

  for (int t = 0; t < 20; ++t){
    k_ka<<<BATCH*NN/256, 256, 0, stream>>>(X, G0, G1);
    for (int e0 = 0; e0 < BATCH; e0 += CH){
      k_p1<<<dim3(N,CH), 256, 0, stream>>>(G0, G1, K, M, Z, Wtab, e0);
      k_colpass<<<dim3(64,CH), CPT, 0, stream>>>(Z, HfC, RdC, Wtab);
      k_p5<<<dim3(N,CH), 256, 0, stream>>>(Z, X, K, M, y, Wtab, e0);
    }
  }
  k_crop<<<(BATCH*512*512)/256, 256, 0, stream>>>(X, out);
}

// Round 4
// 3847.634 us; speedup vs baseline: 1.3545x; 1.1852x over previous
//
#include <hip/hip_runtime.h>
#include <math.h>

#define N 1024
#define NN (1024*1024)
#define BATCH 8

static constexpr float MU1 = 1e-6f, MU2 = 1e-5f, MU3 = 1e-5f;

__device__ __forceinline__ float2 cmulf(float2 a, float2 b){
  return make_float2(a.x*b.x - a.y*b.y, a.x*b.y + a.y*b.x);
}
__device__ __forceinline__ float softf(float v, float T){
  float a = fmaxf(fabsf(v) - T, 0.f);
  return copysignf(a, v);
}
// base-4 digit reversal of 10-bit index (involution)
__device__ __forceinline__ int rev4_10(int p){
  return ((p&3)<<8) | (((p>>2)&3)<<6) | (((p>>4)&3)<<4) | (((p>>6)&3)<<2) | ((p>>8)&3);
}
// folded column order: Hermitian pairs adjacent, complete within any 8-group
__device__ __forceinline__ int foldc(int k){
  if (k == 0) return 0;
  if (k == 512) return 1;
  return (k < 512) ? 2*k : 2*(1024-k)+1;
}
__device__ __forceinline__ int unfoldc(int c){
  if (c < 2) return c ? 512 : 0;
  return (c & 1) ? 1024 - ((c-1)>>1) : (c>>1);
}

// ---------------- 1024-pt Stockham radix-2 FFT in LDS (row passes) ----------
template<int DIR>
__device__ __forceinline__ void fft1024(float2* bufA, float2* bufB,
                                        const float2* Ws, int tid){
  float2* cur = bufA; float2* oth = bufB;
  int s = 1;
  for (int st = 0; st < 10; ++st){
    int m = 512 >> st;
    #pragma unroll
    for (int bb = 0; bb < 2; ++bb){
      int b = tid + bb*256;
      int p = b >> st;
      int q = b & (s-1);
      float2 a = cur[b];
      float2 c = cur[b + 512];
      float2 w = Ws[b & ~(s-1)];
      if (DIR > 0) w.y = -w.y;
      float2 d = make_float2(a.x - c.x, a.y - c.y);
      oth[q + s*(2*p)]   = make_float2(a.x + c.x, a.y + c.y);
      oth[q + s*(2*p+1)] = cmulf(d, w);
    }
    __syncthreads();
    float2* t = cur; cur = oth; oth = t;
    s <<= 1;
  }
}

// ---------------- precompute ----------------
__global__ void k_twiddle(float2* W){
  int j = blockIdx.x*blockDim.x + threadIdx.x;
  if (j < 768){
    double a = -2.0 * M_PI * (double)j / 1024.0;
    W[j] = make_float2((float)cos(a), (float)sin(a));
  }
}

__global__ void k_build_h(const float* __restrict__ h, float2* __restrict__ Z){
  int idx = blockIdx.x*256 + threadIdx.x; // NN
  int i = idx >> 10, j = idx & 1023;
  float v = 0.f;
  if (i >= 256 && i < 768 && j >= 256 && j < 768)
    v = h[(i-256)*512 + (j-256)];
  Z[idx] = make_float2(v, 0.f);
}

// ZT[idx] = fft2(pad h) at (k_j = idx>>10, k_i = idx&1023).
// Colpass layout: [p][colp], k_i = rev4(p), k_j = unfold(colp).
__global__ void k_filters2(const float2* __restrict__ ZT, float2* __restrict__ HfC,
                           float* __restrict__ RdC){
  int id = blockIdx.x*256 + threadIdx.x; // NN
  int p = id >> 10, cp = id & 1023;
  int ki = rev4_10(p);
  int kj = unfoldc(cp);
  float2 v = ZT[((size_t)kj << 10) | (size_t)ki];
  float sgn = ((ki + kj) & 1) ? -1.f : 1.f;
  HfC[id] = make_float2(sgn*v.x, sgn*v.y);
  double mag2 = (double)v.x*(double)v.x + (double)v.y*(double)v.y;
  double ltl = 4.0 - 2.0*cos(2.0*M_PI*(double)ki/1024.0)
                   - 2.0*cos(2.0*M_PI*(double)kj/1024.0);
  double rd = 1.0 / ((double)MU1*mag2 + (double)MU2*ltl + (double)MU3);
  RdC[id] = (float)(rd / ((double)N * (double)N));
}

// X=G0=G1=K=0 ; M0 = MU1 * Vdiv * CTy
__global__ void k_init(float* __restrict__ X, float* __restrict__ G0,
                       float* __restrict__ G1, float* __restrict__ K,
                       float* __restrict__ M, const float* __restrict__ y){
  int idx = blockIdx.x*256 + threadIdx.x; // BATCH*NN
  int e = idx >> 20, r = (idx >> 10) & 1023, c = idx & 1023;
  X[idx] = 0.f; G0[idx] = 0.f; G1[idx] = 0.f; K[idx] = 0.f;
  float m = 0.f;
  if (r >= 256 && r < 768 && c >= 256 && c < 768)
    m = y[(size_t)e*262144 + (size_t)(r-256)*512 + (c-256)] * (MU1/(1.f + MU1));
  M[idx] = m;
}

// ---------------- G (U-dual) update ----------------
__global__ void k_ka(const float* __restrict__ X, float* __restrict__ G0,
                     float* __restrict__ G1){
  int idx = blockIdx.x*256 + threadIdx.x; // BATCH*NN
  int e = idx >> 20, r = (idx >> 10) & 1023, c = idx & 1023;
  size_t eb = (size_t)e * NN;
  float x   = X[idx];
  float xmr = X[eb + (size_t)((r-1)&1023)*N + c];
  float xmc = X[eb + (size_t)r*N + ((c-1)&1023)];
  float psi0 = xmr - x, psi1 = xmc - x;
  float g0 = G0[idx], g1 = G1[idx];
  const float T = 1e4f;              // TAU/MU2
  float u0 = softf(2.f*psi0 - g0*(1.f/MU2), T);
  float u1 = softf(2.f*psi1 - g1*(1.f/MU2), T);
  G0[idx] = MU2*(u0 - psi0) + g0;
  G1[idx] = MU2*(u1 - psi1) + g1;
}

// ---------------- p1: z = s + i*M per row, row FFT, folded-col write ----------
__global__ __launch_bounds__(256) void k_p1(const float* __restrict__ G0,
                                            const float* __restrict__ G1,
                                            const float* __restrict__ K,
                                            const float* __restrict__ M,
                                            float2* __restrict__ Z,
                                            const float2* __restrict__ Wg, int e0){
  __shared__ float2 bufA[N], bufB[N], Ws[512];
  int tid = threadIdx.x;
  int i = blockIdx.x, c = blockIdx.y, e = e0 + c;
  size_t rb  = (size_t)e*NN + (size_t)i*N;
  size_t rb1 = (size_t)e*NN + (size_t)((i+1)&1023)*N;
  size_t zb  = (size_t)c*NN + (size_t)i*N;
  for (int k = tid; k < 512; k += 256) Ws[k] = Wg[k];
  for (int j = tid; j < N; j += 256){
    int jp = (j+1) & 1023;
    float s = K[rb+j] + (G0[rb1+j] - G0[rb+j]) + (G1[rb+jp] - G1[rb+j]);
    bufA[j] = make_float2(s, M[rb+j]);
  }
  __syncthreads();
  fft1024<-1>(bufA, bufB, Ws, tid);
  for (int j = tid; j < N; j += 256) bufB[foldc(j)] = bufA[j];
  __syncthreads();
  for (int j = tid; j < N; j += 256) Z[zb+j] = bufB[j];
}

// ---------------- generic in-place row FFT (precompute only) ----------------
template<int DIR>
__global__ __launch_bounds__(256) void k_fft_row(float2* Z, const float2* __restrict__ Wg){
  __shared__ float2 bufA[N], bufB[N], Ws[512];
  int tid = threadIdx.x;
  size_t base = ((size_t)blockIdx.y * N + blockIdx.x) * N;
  for (int k = tid; k < 512; k += 256) Ws[k] = Wg[k];
  for (int k = tid; k < N; k += 256) bufA[k] = Z[base + k];
  __syncthreads();
  fft1024<DIR>(bufA, bufB, Ws, tid);
  for (int k = tid; k < N; k += 256) Z[base + k] = bufA[k];
}

// ---------------- in-place square transpose (precompute only) ----------------
__global__ void k_transpose_ip(float2* Z){
  __shared__ float2 ta[32][33], tb[32][33];
  int t = blockIdx.x, ti = 0;
  while (t >= 32 - ti){ t -= 32 - ti; ti++; }
  int tj = ti + t;
  size_t base = (size_t)blockIdx.y * NN;
  int ra = ti*32, ca = tj*32;
  for (int k = threadIdx.y; k < 32; k += 8){
    ta[k][threadIdx.x] = Z[base + (size_t)(ra+k)*N + ca + threadIdx.x];
    if (ti != tj)
      tb[k][threadIdx.x] = Z[base + (size_t)(ca+k)*N + ra + threadIdx.x];
  }
  __syncthreads();
  for (int k = threadIdx.y; k < 32; k += 8){
    Z[base + (size_t)(ra+k)*N + ca + threadIdx.x] = (ti!=tj) ? tb[threadIdx.x][k]
                                                             : ta[threadIdx.x][k];
    if (ti != tj)
      Z[base + (size_t)(ca+k)*N + ra + threadIdx.x] = ta[threadIdx.x][k];
  }
}

// ---------------- fused column pass: radix-4 DIF + combine + radix-4 DIT ------
// 8 folded columns x 1024 rows per block; LDS 79.9KB -> 2 blocks/CU, 512 thr.
// Forward DIF leaves base-4 digit-reversed row order; combine in that space;
// inverse DIT consumes digit-reversed order -> natural.
#define CPV 512
__global__ __launch_bounds__(CPV, 4) void k_colpass(float2* __restrict__ Z,
    const float2* __restrict__ HfC, const float* __restrict__ RdC,
    const float2* __restrict__ Wg){
  __shared__ float2 tile[1024][9];   // 8 cols + pad
  __shared__ float2 Ws[768];
  int tid = threadIdx.x;
  int blk = blockIdx.x;              // 128 col-groups of 8
  size_t zbase = (size_t)blockIdx.y*NN + ((size_t)blk<<3);
  for (int k = tid; k < 768; k += CPV) Ws[k] = Wg[k];
  for (int k = tid; k < 8192; k += CPV){
    int r = k >> 3, c = k & 7;
    tile[r][c] = Z[zbase + (size_t)r*N + c];
  }
  __syncthreads();
  // forward radix-4 DIF: 5 stages
  #pragma unroll
  for (int s = 0; s < 5; ++s){
    int log2L = 8 - 2*s;
    int L = 1 << log2L;
    for (int k = tid; k < 2048; k += CPV){
      int c = k & 7, t = k >> 3;       // t in [0,256)
      int j = t & (L-1);
      int base = ((t >> log2L) << (log2L + 2)) + j;
      float2 x0 = tile[base][c],     x1 = tile[base+L][c],
             x2 = tile[base+2*L][c], x3 = tile[base+3*L][c];
      float2 t02p = make_float2(x0.x+x2.x, x0.y+x2.y);
      float2 t02m = make_float2(x0.x-x2.x, x0.y-x2.y);
      float2 t13p = make_float2(x1.x+x3.x, x1.y+x3.y);
      float2 t13m = make_float2(x1.x-x3.x, x1.y-x3.y);
      float2 u0 = make_float2(t02p.x+t13p.x, t02p.y+t13p.y);
      float2 u2 = make_float2(t02p.x-t13p.x, t02p.y-t13p.y);
      float2 u1 = make_float2(t02m.x+t13m.y, t02m.y-t13m.x);  // t02m - i*t13m
      float2 u3 = make_float2(t02m.x-t13m.y, t02m.y+t13m.x);  // t02m + i*t13m
      int tw = j << (2*s);
      tile[base][c]     = u0;
      tile[base+L][c]   = cmulf(u1, Ws[tw]);
      tile[base+2*L][c] = cmulf(u2, Ws[2*tw]);
      tile[base+3*L][c] = cmulf(u3, Ws[3*tw]);
    }
    __syncthreads();
  }
  // spectral combine on Hermitian pairs (rev4 position space)
  int colbase = blk << 3;
  for (int k = tid; k < 8192; k += CPV){
    int p = k >> 3, c = k & 7;
    int k1 = rev4_10(p);
    int q = rev4_10((1024 - k1) & 1023);
    int colp = colbase + c;
    int cm = (colp < 2) ? c : (c ^ 1);
    int pid = (q << 3) | cm;
    if (pid < k) continue;
    float2 Zk = tile[p][c];
    float2 Zr = tile[q][cm];
    float Sre = 0.5f*(Zk.x + Zr.x);
    float Sim = 0.5f*(Zk.y - Zr.y);
    float Mre = 0.5f*(Zk.y + Zr.y);
    float Mim = 0.5f*(Zr.x - Zk.x);
    size_t fidx = ((size_t)p << 10) | (size_t)colp;
    float2 hf = HfC[fidx];
    float rd  = RdC[fidx];
    float fr = rd*(Sre + hf.x*Mre + hf.y*Mim);
    float fi = rd*(Sim + hf.x*Mim - hf.y*Mre);
    float hr = hf.x*fr - hf.y*fi;
    float hi = hf.x*fi + hf.y*fr;
    tile[p][c] = make_float2(fr - hi, fi + hr);
    if (pid != k) tile[q][cm] = make_float2(fr + hi, hr - fi);
  }
  __syncthreads();
  // inverse radix-4 DIT: 5 stages (digit-reversed in -> natural out)
  #pragma unroll
  for (int s = 0; s < 5; ++s){
    int H = 1 << (2*s);
    for (int k = tid; k < 2048; k += CPV){
      int c = k & 7, t = k >> 3;
      int j = t & (H-1);
      int base = ((t >> (2*s)) << (2*s + 2)) + j;
      float2 x0 = tile[base][c],     x1 = tile[base+H][c],
             x2 = tile[base+2*H][c], x3 = tile[base+3*H][c];
      int tw = j << (8 - 2*s);
      float2 w1 = Ws[tw];   w1.y = -w1.y;
      float2 w2 = Ws[2*tw]; w2.y = -w2.y;
      float2 w3 = Ws[3*tw]; w3.y = -w3.y;
      float2 v1 = cmulf(x1, w1), v2 = cmulf(x2, w2), v3 = cmulf(x3, w3);
      float2 t02p = make_float2(x0.x+v2.x, x0.y+v2.y);
      float2 t02m = make_float2(x0.x-v2.x, x0.y-v2.y);
      float2 t13p = make_float2(v1.x+v3.x, v1.y+v3.y);
      float2 t13m = make_float2(v1.x-v3.x, v1.y-v3.y);
      tile[base][c]     = make_float2(t02p.x+t13p.x, t02p.y+t13p.y);
      tile[base+2*H][c] = make_float2(t02p.x-t13p.x, t02p.y-t13p.y);
      tile[base+H][c]   = make_float2(t02m.x-t13m.y, t02m.y+t13m.x); // +i*t13m
      tile[base+3*H][c] = make_float2(t02m.x+t13m.y, t02m.y-t13m.x); // -i*t13m
    }
    __syncthreads();
  }
  for (int k = tid; k < 8192; k += CPV){
    int r = k >> 3, c = k & 7;
    Z[zbase + (size_t)r*N + c] = tile[r][c];
  }
}

// ---------------- p5: unfold + inverse row FFT; write X; fused K,M updates ----
__global__ __launch_bounds__(256) void k_p5(const float2* __restrict__ Z,
                                            float* __restrict__ X, float* __restrict__ K,
                                            float* __restrict__ M, const float* __restrict__ y,
                                            const float2* __restrict__ Wg, int e0){
  __shared__ float2 bufA[N], bufB[N], Ws[512];
  int tid = threadIdx.x;
  int i = blockIdx.x, c = blockIdx.y, e = e0 + c;
  size_t zb = (size_t)c*NN + (size_t)i*N;
  size_t sb = (size_t)e*NN + (size_t)i*N;
  for (int k = tid; k < 512; k += 256) Ws[k] = Wg[k];
  for (int k = tid; k < N; k += 256) bufB[k] = Z[zb + k];
  __syncthreads();
  for (int k = tid; k < N; k += 256) bufA[k] = bufB[foldc(k)];
  __syncthreads();
  fft1024<1>(bufA, bufB, Ws, tid);
  bool rcent = (i >= 256 && i < 768);
  for (int j = tid; j < N; j += 256){
    float x = bufA[j].x, hx = bufA[j].y;
    X[sb+j] = x;
    float kk = K[sb+j];
    float w = fmaxf(2.f*x - kk*(1.f/MU3), 0.f);
    K[sb+j] = MU3*(w - x) + kk;
    float m = M[sb+j];
    bool cent = rcent && (j >= 256 && j < 768);
    float cty  = cent ? y[(size_t)e*262144 + (size_t)(i-256)*512 + (j-256)] : 0.f;
    float vdiv = cent ? (1.f/(1.f + MU1)) : (1.f/MU1);
    float v = vdiv*(2.f*MU1*hx - m + cty);
    M[sb+j] = MU1*(v - hx) + m;
  }
}

__global__ void k_crop(const float* __restrict__ X, float* __restrict__ out){
  int t = blockIdx.x*256 + threadIdx.x; // 8*512*512
  int e = t >> 18;
  int r = (t >> 9) & 511;
  int c = t & 511;
  out[t] = X[(size_t)e*NN + (size_t)(r+256)*N + (c+256)];
}

extern "C" void kernel_launch(void* const* d_in, const int* in_sizes, int n_in,
                              void* d_out, int out_size, void* d_ws, size_t ws_size,
                              hipStream_t stream){
  const float* y = (const float*)d_in[0];   // (8,1,512,512)
  const float* h = (const float*)d_in[1];   // (512,512)
  float* out = (float*)d_out;

  size_t fplane = (size_t)BATCH * NN;
  float* X  = (float*)d_ws;
  float* G0 = X  + fplane;
  float* G1 = G0 + fplane;
  float* K  = G1 + fplane;
  float* M  = K  + fplane;
  float2* HfC  = (float2*)(M + fplane);
  float*  RdC  = (float*)(HfC + NN);
  float2* Wtab = (float2*)(RdC + NN);
  float2* Zws  = Wtab + 768;
  size_t used = (size_t)((char*)Zws - (char*)d_ws);

  int CH = 0;
  for (int c = BATCH; c >= 1; c >>= 1)
    if (used + (size_t)c * NN * sizeof(float2) <= ws_size){ CH = c; break; }
  float2* Z = (CH > 0) ? Zws : (float2*)d_out;  // d_out is exactly NN float2
  if (CH == 0) CH = 1;

  // precompute: twiddles, fft2(pad h) in Z plane 0, filters in colpass layout
  k_twiddle<<<3, 256, 0, stream>>>(Wtab);
  k_build_h<<<NN/256, 256, 0, stream>>>(h, Z);
  k_fft_row<-1><<<dim3(N,1), 256, 0, stream>>>(Z, Wtab);
  k_transpose_ip<<<dim3(528,1), dim3(32,8), 0, stream>>>(Z);
  k_fft_row<-1><<<dim3(N,1), 256, 0, stream>>>(Z, Wtab);
  k_filters2<<<NN/256, 256, 0, stream>>>(Z, HfC, RdC);
  k_init<<<BATCH*NN/256, 256, 0, stream>>>(X, G0, G1, K, M, y);

  for (int t = 0; t < 20; ++t){
    k_ka<<<BATCH*NN/256, 256, 0, stream>>>(X, G0, G1);
    for (int e0 = 0; e0 < BATCH; e0 += CH){
      k_p1<<<dim3(N,CH), 256, 0, stream>>>(G0, G1, K, M, Z, Wtab, e0);
      k_colpass<<<dim3(128,CH), CPV, 0, stream>>>(Z, HfC, RdC, Wtab);
      k_p5<<<dim3(N,CH), 256, 0, stream>>>(Z, X, K, M, y, Wtab, e0);
    }
  }
  k_crop<<<(BATCH*512*512)/256, 256, 0, stream>>>(X, out);
}

// Round 5
// 3769.335 us; speedup vs baseline: 1.3826x; 1.0208x over previous
//
#include <hip/hip_runtime.h>
#include <math.h>

#define N 1024
#define NN (1024*1024)
#define BATCH 8

static constexpr float MU1 = 1e-6f, MU2 = 1e-5f, MU3 = 1e-5f;

__device__ __forceinline__ float2 cmulf(float2 a, float2 b){
  return make_float2(a.x*b.x - a.y*b.y, a.x*b.y + a.y*b.x);
}
__device__ __forceinline__ float2 conjf(float2 a){ return make_float2(a.x, -a.y); }
__device__ __forceinline__ float softf(float v, float T){
  float a = fmaxf(fabsf(v) - T, 0.f);
  return copysignf(a, v);
}
// base-4 digit reversal of 10-bit index (involution)
__device__ __forceinline__ int rev4_10(int p){
  return ((p&3)<<8) | (((p>>2)&3)<<6) | (((p>>4)&3)<<4) | (((p>>6)&3)<<2) | ((p>>8)&3);
}
// folded column order: Hermitian pairs adjacent, complete within any 8-group
__device__ __forceinline__ int foldc(int k){
  if (k == 0) return 0;
  if (k == 512) return 1;
  return (k < 512) ? 2*k : 2*(1024-k)+1;
}
__device__ __forceinline__ int unfoldc(int c){
  if (c < 2) return c ? 512 : 0;
  return (c & 1) ? 1024 - ((c-1)>>1) : (c>>1);
}

// radix-4 butterflies (forward uses e^{-i}, inverse e^{+i}); inputs pre-twiddled for inverse
#define BF4F(x0,x1,x2,x3,u0,u1,u2,u3) { \
  float2 t02p = make_float2((x0).x+(x2).x, (x0).y+(x2).y); \
  float2 t02m = make_float2((x0).x-(x2).x, (x0).y-(x2).y); \
  float2 t13p = make_float2((x1).x+(x3).x, (x1).y+(x3).y); \
  float2 t13m = make_float2((x1).x-(x3).x, (x1).y-(x3).y); \
  u0 = make_float2(t02p.x+t13p.x, t02p.y+t13p.y); \
  u2 = make_float2(t02p.x-t13p.x, t02p.y-t13p.y); \
  u1 = make_float2(t02m.x+t13m.y, t02m.y-t13m.x); \
  u3 = make_float2(t02m.x-t13m.y, t02m.y+t13m.x); }
#define BF4I(x0,x1,x2,x3,u0,u1,u2,u3) { \
  float2 t02p = make_float2((x0).x+(x2).x, (x0).y+(x2).y); \
  float2 t02m = make_float2((x0).x-(x2).x, (x0).y-(x2).y); \
  float2 t13p = make_float2((x1).x+(x3).x, (x1).y+(x3).y); \
  float2 t13m = make_float2((x1).x-(x3).x, (x1).y-(x3).y); \
  u0 = make_float2(t02p.x+t13p.x, t02p.y+t13p.y); \
  u2 = make_float2(t02p.x-t13p.x, t02p.y-t13p.y); \
  u1 = make_float2(t02m.x-t13m.y, t02m.y+t13m.x); \
  u3 = make_float2(t02m.x+t13m.y, t02m.y-t13m.x); }

// ---------------- 1024-pt Stockham radix-2 FFT in LDS (row passes) ----------
template<int DIR>
__device__ __forceinline__ void fft1024(float2* bufA, float2* bufB,
                                        const float2* Ws, int tid){
  float2* cur = bufA; float2* oth = bufB;
  int s = 1;
  for (int st = 0; st < 10; ++st){
    int m = 512 >> st;
    #pragma unroll
    for (int bb = 0; bb < 2; ++bb){
      int b = tid + bb*256;
      int p = b >> st;
      int q = b & (s-1);
      float2 a = cur[b];
      float2 c = cur[b + 512];
      float2 w = Ws[b & ~(s-1)];
      if (DIR > 0) w.y = -w.y;
      float2 d = make_float2(a.x - c.x, a.y - c.y);
      oth[q + s*(2*p)]   = make_float2(a.x + c.x, a.y + c.y);
      oth[q + s*(2*p+1)] = cmulf(d, w);
    }
    __syncthreads();
    float2* t = cur; cur = oth; oth = t;
    s <<= 1;
  }
}

// ---------------- precompute ----------------
__global__ void k_twiddle(float2* W){
  int j = blockIdx.x*blockDim.x + threadIdx.x;
  if (j < 768){
    double a = -2.0 * M_PI * (double)j / 1024.0;
    W[j] = make_float2((float)cos(a), (float)sin(a));
  }
}

__global__ void k_build_h(const float* __restrict__ h, float2* __restrict__ Z){
  int idx = blockIdx.x*256 + threadIdx.x; // NN
  int i = idx >> 10, j = idx & 1023;
  float v = 0.f;
  if (i >= 256 && i < 768 && j >= 256 && j < 768)
    v = h[(i-256)*512 + (j-256)];
  Z[idx] = make_float2(v, 0.f);
}

// ZT[idx] = fft2(pad h) at (k_j = idx>>10, k_i = idx&1023).
// Blocked colpass layout: HfCb[blk][p][c], k_i = rev4(p), k_j = unfold(blk*8+c).
__global__ void k_filters2(const float2* __restrict__ ZT, float2* __restrict__ HfCb,
                           float* __restrict__ RdCb){
  int id = blockIdx.x*256 + threadIdx.x; // NN
  int blk = id >> 13;
  int rem = id & 8191;
  int p = rem >> 3, c = rem & 7;
  int colp = (blk << 3) | c;
  int ki = rev4_10(p);
  int kj = unfoldc(colp);
  float2 v = ZT[((size_t)kj << 10) | (size_t)ki];
  float sgn = ((ki + kj) & 1) ? -1.f : 1.f;
  HfCb[id] = make_float2(sgn*v.x, sgn*v.y);
  double mag2 = (double)v.x*(double)v.x + (double)v.y*(double)v.y;
  double ltl = 4.0 - 2.0*cos(2.0*M_PI*(double)ki/1024.0)
                   - 2.0*cos(2.0*M_PI*(double)kj/1024.0);
  double rd = 1.0 / ((double)MU1*mag2 + (double)MU2*ltl + (double)MU3);
  RdCb[id] = (float)(rd / ((double)N * (double)N));
}

// X=G1=K=G0a=G0b=0 ; M0 = MU1 * Vdiv * CTy
__global__ void k_init(float* __restrict__ X, float* __restrict__ G1,
                       float* __restrict__ K, float* __restrict__ M,
                       float* __restrict__ G0a, float* __restrict__ G0b,
                       const float* __restrict__ y){
  int idx = blockIdx.x*256 + threadIdx.x; // BATCH*NN
  int e = idx >> 20, r = (idx >> 10) & 1023, c = idx & 1023;
  X[idx] = 0.f; G1[idx] = 0.f; K[idx] = 0.f; G0a[idx] = 0.f; G0b[idx] = 0.f;
  float m = 0.f;
  if (r >= 256 && r < 768 && c >= 256 && c < 768)
    m = y[(size_t)e*262144 + (size_t)(r-256)*512 + (c-256)] * (MU1/(1.f + MU1));
  M[idx] = m;
}

// ---------------- pA: fused G0-update + s-build + forward row FFT ------------
// G0 ping-pong: read G0r (rows i, i+1), write G0w (row i); recompute row i+1 locally.
// s = K + (G0'[i+1]-G0'[i]) + (G1[i][j+1]-G1[i][j]);  z = s + i*M; folded-col out.
__global__ __launch_bounds__(256) void k_pA(const float* __restrict__ X,
                                            const float* __restrict__ G0r,
                                            float* __restrict__ G0w,
                                            const float* __restrict__ G1,
                                            const float* __restrict__ K,
                                            const float* __restrict__ M,
                                            float2* __restrict__ Z,
                                            const float2* __restrict__ Wg, int e0){
  __shared__ float2 bufA[N], bufB[N], Ws[512];
  int tid = threadIdx.x;
  int bid = blockIdx.x;
  int i = ((bid & 7) << 7) + (bid >> 3);   // XCD row-chunk swizzle
  int ce = blockIdx.y, e = e0 + ce;
  size_t eb  = (size_t)e*NN;
  size_t rb  = eb + (size_t)i*N;
  size_t rbm = eb + (size_t)((i-1)&1023)*N;
  size_t rbp = eb + (size_t)((i+1)&1023)*N;
  size_t zb  = (size_t)ce*NN + (size_t)i*N;
  for (int k = tid; k < 512; k += 256) Ws[k] = Wg[k];
  const float T = 1e4f;                    // TAU/MU2
  for (int j = tid; j < N; j += 256){
    float xm = X[rbm+j], x = X[rb+j], xp = X[rbp+j];
    float psi0  = xm - x;
    float psi0p = x - xp;                  // psi0 at row i+1
    float g0  = G0r[rb+j], g0p = G0r[rbp+j];
    float u0  = softf(2.f*psi0  - g0 *(1.f/MU2), T);
    float u0p = softf(2.f*psi0p - g0p*(1.f/MU2), T);
    float g0n  = MU2*(u0  - psi0 ) + g0;
    float g0np = MU2*(u0p - psi0p) + g0p;
    G0w[rb+j] = g0n;
    int jp = (j+1) & 1023;
    float s = K[rb+j] + (g0np - g0n) + (G1[rb+jp] - G1[rb+j]);
    bufA[j] = make_float2(s, M[rb+j]);
  }
  __syncthreads();
  fft1024<-1>(bufA, bufB, Ws, tid);
  for (int j = tid; j < N; j += 256) bufB[foldc(j)] = bufA[j];
  __syncthreads();
  for (int j = tid; j < N; j += 256) Z[zb+j] = bufB[j];
}

// ---------------- generic in-place row FFT (precompute only) ----------------
template<int DIR>
__global__ __launch_bounds__(256) void k_fft_row(float2* Z, const float2* __restrict__ Wg){
  __shared__ float2 bufA[N], bufB[N], Ws[512];
  int tid = threadIdx.x;
  size_t base = ((size_t)blockIdx.y * N + blockIdx.x) * N;
  for (int k = tid; k < 512; k += 256) Ws[k] = Wg[k];
  for (int k = tid; k < N; k += 256) bufA[k] = Z[base + k];
  __syncthreads();
  fft1024<DIR>(bufA, bufB, Ws, tid);
  for (int k = tid; k < N; k += 256) Z[base + k] = bufA[k];
}

// ---------------- in-place square transpose (precompute only) ----------------
__global__ void k_transpose_ip(float2* Z){
  __shared__ float2 ta[32][33], tb[32][33];
  int t = blockIdx.x, ti = 0;
  while (t >= 32 - ti){ t -= 32 - ti; ti++; }
  int tj = ti + t;
  size_t base = (size_t)blockIdx.y * NN;
  int ra = ti*32, ca = tj*32;
  for (int k = threadIdx.y; k < 32; k += 8){
    ta[k][threadIdx.x] = Z[base + (size_t)(ra+k)*N + ca + threadIdx.x];
    if (ti != tj)
      tb[k][threadIdx.x] = Z[base + (size_t)(ca+k)*N + ra + threadIdx.x];
  }
  __syncthreads();
  for (int k = threadIdx.y; k < 32; k += 8){
    Z[base + (size_t)(ra+k)*N + ca + threadIdx.x] = (ti!=tj) ? tb[threadIdx.x][k]
                                                             : ta[threadIdx.x][k];
    if (ti != tj)
      Z[base + (size_t)(ca+k)*N + ra + threadIdx.x] = ta[threadIdx.x][k];
  }
}

// ---------------- fused column pass: radix-4 (2 stages/sync) + combine -------
// 8 folded cols x 1024 rows; XOR-swizzled LDS addr: (9r+c)^((r&16)>>1)
#define TADDR(r,c) ((((r)*9) + (c)) ^ (((r) & 16) >> 1))
#define CPV 512
__global__ __launch_bounds__(CPV, 4) void k_colpass(float2* __restrict__ Z,
    const float2* __restrict__ HfCb, const float* __restrict__ RdCb,
    const float2* __restrict__ Wg){
  __shared__ float2 tile[9216];
  __shared__ float2 Ws[768];
  int tid = threadIdx.x;
  int blk = blockIdx.x;              // 128 col-groups of 8
  size_t zbase = (size_t)blockIdx.y*NN + ((size_t)blk<<3);
  for (int k = tid; k < 768; k += CPV) Ws[k] = Wg[k];
  for (int k = tid; k < 8192; k += CPV){
    int r = k >> 3, c = k & 7;
    tile[TADDR(r,c)] = Z[zbase + (size_t)r*N + c];
  }
  __syncthreads();
  // ---- forward stages 0+1 (rows j2 + 64b + 256a) ----
  {
    int c = tid & 7, j2 = tid >> 3;
    float2 v[4][4];
    #pragma unroll
    for (int a = 0; a < 4; ++a)
      #pragma unroll
      for (int b = 0; b < 4; ++b)
        v[a][b] = tile[TADDR(j2 + 64*b + 256*a, c)];
    #pragma unroll
    for (int b = 0; b < 4; ++b){
      int j1 = j2 + 64*b;
      float2 u0,u1,u2,u3;
      BF4F(v[0][b],v[1][b],v[2][b],v[3][b],u0,u1,u2,u3);
      v[0][b] = u0;
      v[1][b] = cmulf(u1, Ws[j1]);
      v[2][b] = cmulf(u2, Ws[2*j1]);
      v[3][b] = cmulf(u3, Ws[3*j1]);
    }
    int tw = j2 << 2;
    #pragma unroll
    for (int a = 0; a < 4; ++a){
      float2 u0,u1,u2,u3;
      BF4F(v[a][0],v[a][1],v[a][2],v[a][3],u0,u1,u2,u3);
      tile[TADDR(j2 + 256*a, c)]       = u0;
      tile[TADDR(j2 + 64 + 256*a, c)]  = cmulf(u1, Ws[tw]);
      tile[TADDR(j2 + 128 + 256*a, c)] = cmulf(u2, Ws[2*tw]);
      tile[TADDR(j2 + 192 + 256*a, c)] = cmulf(u3, Ws[3*tw]);
    }
  }
  __syncthreads();
  // ---- forward stages 2+3 (rows 64*B2 + j2 + 4b + 16a) ----
  {
    int c = tid & 7, vv = tid >> 3;
    int B2 = vv >> 2, j2 = vv & 3;
    int r0 = 64*B2 + j2;
    float2 v[4][4];
    #pragma unroll
    for (int a = 0; a < 4; ++a)
      #pragma unroll
      for (int b = 0; b < 4; ++b)
        v[a][b] = tile[TADDR(r0 + 4*b + 16*a, c)];
    #pragma unroll
    for (int b = 0; b < 4; ++b){
      int tw = (j2 + 4*b) << 4;
      float2 u0,u1,u2,u3;
      BF4F(v[0][b],v[1][b],v[2][b],v[3][b],u0,u1,u2,u3);
      v[0][b] = u0;
      v[1][b] = cmulf(u1, Ws[tw]);
      v[2][b] = cmulf(u2, Ws[2*tw]);
      v[3][b] = cmulf(u3, Ws[3*tw]);
    }
    int tw3 = j2 << 6;
    #pragma unroll
    for (int a = 0; a < 4; ++a){
      float2 u0,u1,u2,u3;
      BF4F(v[a][0],v[a][1],v[a][2],v[a][3],u0,u1,u2,u3);
      tile[TADDR(r0 + 16*a, c)]      = u0;
      tile[TADDR(r0 + 16*a + 4, c)]  = cmulf(u1, Ws[tw3]);
      tile[TADDR(r0 + 16*a + 8, c)]  = cmulf(u2, Ws[2*tw3]);
      tile[TADDR(r0 + 16*a + 12, c)] = cmulf(u3, Ws[3*tw3]);
    }
  }
  __syncthreads();
  // ---- forward stage 4 (rows 4t + a, no twiddle) ----
  for (int k = tid; k < 2048; k += CPV){
    int c = k & 7, t = k >> 3;
    int r = 4*t;
    float2 x0 = tile[TADDR(r,c)],   x1 = tile[TADDR(r+1,c)];
    float2 x2 = tile[TADDR(r+2,c)], x3 = tile[TADDR(r+3,c)];
    float2 u0,u1,u2,u3;
    BF4F(x0,x1,x2,x3,u0,u1,u2,u3);
    tile[TADDR(r,c)] = u0; tile[TADDR(r+1,c)] = u1;
    tile[TADDR(r+2,c)] = u2; tile[TADDR(r+3,c)] = u3;
  }
  __syncthreads();
  // ---- spectral combine on Hermitian pairs (rev4 position space) ----
  {
    size_t fbase = (size_t)blk << 13;
    for (int k = tid; k < 8192; k += CPV){
      int p = k >> 3, c = k & 7;
      int k1 = rev4_10(p);
      int q = rev4_10((1024 - k1) & 1023);
      int colp = (blk << 3) + c;
      int cm = (colp < 2) ? c : (c ^ 1);
      int pid = (q << 3) | cm;
      if (pid < k) continue;
      float2 Zk = tile[TADDR(p,c)];
      float2 Zr = tile[TADDR(q,cm)];
      float Sre = 0.5f*(Zk.x + Zr.x);
      float Sim = 0.5f*(Zk.y - Zr.y);
      float Mre = 0.5f*(Zk.y + Zr.y);
      float Mim = 0.5f*(Zr.x - Zk.x);
      float2 hf = HfCb[fbase + k];
      float rd  = RdCb[fbase + k];
      float fr = rd*(Sre + hf.x*Mre + hf.y*Mim);
      float fi = rd*(Sim + hf.x*Mim - hf.y*Mre);
      float hr = hf.x*fr - hf.y*fi;
      float hi = hf.x*fi + hf.y*fr;
      tile[TADDR(p,c)] = make_float2(fr - hi, fi + hr);
      if (pid != k) tile[TADDR(q,cm)] = make_float2(fr + hi, hr - fi);
    }
  }
  __syncthreads();
  // ---- inverse stages 0+1 (rows 16G + 4a + b) ----
  {
    int c = tid & 7, G = tid >> 3;
    int r0 = 16*G;
    float2 v[4][4];
    #pragma unroll
    for (int a = 0; a < 4; ++a)
      #pragma unroll
      for (int b = 0; b < 4; ++b)
        v[a][b] = tile[TADDR(r0 + 4*a + b, c)];
    #pragma unroll
    for (int a = 0; a < 4; ++a){
      float2 u0,u1,u2,u3;
      BF4I(v[a][0],v[a][1],v[a][2],v[a][3],u0,u1,u2,u3);
      v[a][0]=u0; v[a][1]=u1; v[a][2]=u2; v[a][3]=u3;
    }
    #pragma unroll
    for (int b = 0; b < 4; ++b){
      int tw = b << 6;
      float2 x0 = v[0][b];
      float2 x1 = cmulf(v[1][b], conjf(Ws[tw]));
      float2 x2 = cmulf(v[2][b], conjf(Ws[2*tw]));
      float2 x3 = cmulf(v[3][b], conjf(Ws[3*tw]));
      float2 u0,u1,u2,u3;
      BF4I(x0,x1,x2,x3,u0,u1,u2,u3);
      tile[TADDR(r0 + b, c)]      = u0;
      tile[TADDR(r0 + 4 + b, c)]  = u1;
      tile[TADDR(r0 + 8 + b, c)]  = u2;
      tile[TADDR(r0 + 12 + b, c)] = u3;
    }
  }
  __syncthreads();
  // ---- inverse stages 2+3 (rows 256*T3 + jj + 16a + 64b) ----
  {
    int c = tid & 7, vv = tid >> 3;
    int T3 = vv >> 4, jj = vv & 15;
    int r0 = 256*T3 + jj;
    float2 v[4][4];
    #pragma unroll
    for (int a = 0; a < 4; ++a)
      #pragma unroll
      for (int b = 0; b < 4; ++b)
        v[a][b] = tile[TADDR(r0 + 16*a + 64*b, c)];
    int tw2 = jj << 4;
    #pragma unroll
    for (int b = 0; b < 4; ++b){
      float2 x0 = v[0][b];
      float2 x1 = cmulf(v[1][b], conjf(Ws[tw2]));
      float2 x2 = cmulf(v[2][b], conjf(Ws[2*tw2]));
      float2 x3 = cmulf(v[3][b], conjf(Ws[3*tw2]));
      float2 u0,u1,u2,u3;
      BF4I(x0,x1,x2,x3,u0,u1,u2,u3);
      v[0][b]=u0; v[1][b]=u1; v[2][b]=u2; v[3][b]=u3;
    }
    #pragma unroll
    for (int a = 0; a < 4; ++a){
      int tw = (jj + 16*a) << 2;
      float2 x0 = v[a][0];
      float2 x1 = cmulf(v[a][1], conjf(Ws[tw]));
      float2 x2 = cmulf(v[a][2], conjf(Ws[2*tw]));
      float2 x3 = cmulf(v[a][3], conjf(Ws[3*tw]));
      float2 u0,u1,u2,u3;
      BF4I(x0,x1,x2,x3,u0,u1,u2,u3);
      tile[TADDR(r0 + 16*a, c)]       = u0;
      tile[TADDR(r0 + 16*a + 64, c)]  = u1;
      tile[TADDR(r0 + 16*a + 128, c)] = u2;
      tile[TADDR(r0 + 16*a + 192, c)] = u3;
    }
  }
  __syncthreads();
  // ---- inverse stage 4 (rows t + 256a, tw = t) ----
  for (int k = tid; k < 2048; k += CPV){
    int c = k & 7, t = k >> 3;
    float2 x0 = tile[TADDR(t,c)];
    float2 x1 = cmulf(tile[TADDR(t+256,c)], conjf(Ws[t]));
    float2 x2 = cmulf(tile[TADDR(t+512,c)], conjf(Ws[2*t]));
    float2 x3 = cmulf(tile[TADDR(t+768,c)], conjf(Ws[3*t]));
    float2 u0,u1,u2,u3;
    BF4I(x0,x1,x2,x3,u0,u1,u2,u3);
    tile[TADDR(t,c)] = u0;     tile[TADDR(t+256,c)] = u1;
    tile[TADDR(t+512,c)] = u2; tile[TADDR(t+768,c)] = u3;
  }
  __syncthreads();
  for (int k = tid; k < 8192; k += CPV){
    int r = k >> 3, c = k & 7;
    Z[zbase + (size_t)r*N + c] = tile[TADDR(r,c)];
  }
}

// ---------------- p5: unfold + inverse row FFT; X,K,M,G1 updates; crop out ---
__global__ __launch_bounds__(256) void k_p5(const float2* __restrict__ Z,
                                            float* __restrict__ X, float* __restrict__ K,
                                            float* __restrict__ M, float* __restrict__ G1,
                                            const float* __restrict__ y,
                                            float* __restrict__ out, int writeOut,
                                            const float2* __restrict__ Wg, int e0){
  __shared__ float2 bufA[N], bufB[N], Ws[512];
  int tid = threadIdx.x;
  int i = blockIdx.x, ce = blockIdx.y, e = e0 + ce;
  size_t zb = (size_t)ce*NN + (size_t)i*N;
  size_t sb = (size_t)e*NN + (size_t)i*N;
  for (int k = tid; k < 512; k += 256) Ws[k] = Wg[k];
  for (int k = tid; k < N; k += 256) bufB[k] = Z[zb + k];
  __syncthreads();
  for (int k = tid; k < N; k += 256) bufA[k] = bufB[foldc(k)];
  __syncthreads();
  fft1024<1>(bufA, bufB, Ws, tid);
  bool rcent = (i >= 256 && i < 768);
  const float T = 1e4f;
  for (int j = tid; j < N; j += 256){
    float x = bufA[j].x, hx = bufA[j].y;
    X[sb+j] = x;
    float kk = K[sb+j];
    float w = fmaxf(2.f*x - kk*(1.f/MU3), 0.f);
    K[sb+j] = MU3*(w - x) + kk;
    float m = M[sb+j];
    bool cent = rcent && (j >= 256 && j < 768);
    float cty  = cent ? y[(size_t)e*262144 + (size_t)(i-256)*512 + (j-256)] : 0.f;
    float vdiv = cent ? (1.f/(1.f + MU1)) : (1.f/MU1);
    float v = vdiv*(2.f*MU1*hx - m + cty);
    M[sb+j] = MU1*(v - hx) + m;
    float xm = bufA[(j-1)&1023].x;
    float psi1 = xm - x;
    float g1 = G1[sb+j];
    float u1 = softf(2.f*psi1 - g1*(1.f/MU2), T);
    G1[sb+j] = MU2*(u1 - psi1) + g1;
    if (writeOut && cent)
      out[(size_t)e*262144 + (size_t)(i-256)*512 + (j-256)] = x;
  }
}

__global__ void k_crop(const float* __restrict__ X, float* __restrict__ out){
  int t = blockIdx.x*256 + threadIdx.x; // 8*512*512
  int e = t >> 18;
  int r = (t >> 9) & 511;
  int c = t & 511;
  out[t] = X[(size_t)e*NN + (size_t)(r+256)*N + (c+256)];
}

extern "C" void kernel_launch(void* const* d_in, const int* in_sizes, int n_in,
                              void* d_out, int out_size, void* d_ws, size_t ws_size,
                              hipStream_t stream){
  const float* y = (const float*)d_in[0];   // (8,1,512,512)
  const float* h = (const float*)d_in[1];   // (512,512)
  float* out = (float*)d_out;

  size_t fplane = (size_t)BATCH * NN;
  float* X   = (float*)d_ws;
  float* G1  = X   + fplane;
  float* K   = G1  + fplane;
  float* M   = K   + fplane;
  float* G0a = M   + fplane;
  float* G0b = G0a + fplane;
  float2* HfCb = (float2*)(G0b + fplane);
  float*  RdCb = (float*)(HfCb + NN);
  float2* Wtab = (float2*)(RdCb + NN);
  float2* Zws  = Wtab + 768;
  size_t used = (size_t)((char*)Zws - (char*)d_ws);

  int CH = 0;
  for (int c = BATCH; c >= 1; c >>= 1)
    if (used + (size_t)c * NN * sizeof(float2) <= ws_size){ CH = c; break; }
  bool fallback = (CH == 0);
  float2* Z = fallback ? (float2*)d_out : Zws;  // d_out is exactly NN float2
  if (CH == 0) CH = 1;

  // precompute: twiddles, fft2(pad h) in Z plane 0, filters in blocked layout
  k_twiddle<<<3, 256, 0, stream>>>(Wtab);
  k_build_h<<<NN/256, 256, 0, stream>>>(h, Z);
  k_fft_row<-1><<<dim3(N,1), 256, 0, stream>>>(Z, Wtab);
  k_transpose_ip<<<dim3(528,1), dim3(32,8), 0, stream>>>(Z);
  k_fft_row<-1><<<dim3(N,1), 256, 0, stream>>>(Z, Wtab);
  k_filters2<<<NN/256, 256, 0, stream>>>(Z, HfCb, RdCb);
  k_init<<<BATCH*NN/256, 256, 0, stream>>>(X, G1, K, M, G0a, G0b, y);

  for (int t = 0; t < 20; ++t){
    const float* G0r = (t & 1) ? G0b : G0a;
    float*       G0w = (t & 1) ? G0a : G0b;
    int wo = (t == 19 && !fallback) ? 1 : 0;
    for (int e0 = 0; e0 < BATCH; e0 += CH){
      k_pA<<<dim3(N,CH), 256, 0, stream>>>(X, G0r, G0w, G1, K, M, Z, Wtab, e0);
      k_colpass<<<dim3(128,CH), CPV, 0, stream>>>(Z, HfCb, RdCb, Wtab);
      k_p5<<<dim3(N,CH), 256, 0, stream>>>(Z, X, K, M, G1, y, out, wo, Wtab, e0);
    }
  }
  if (fallback)
    k_crop<<<(BATCH*512*512)/256, 256, 0, stream>>>(X, out);
}